// Round 12
// baseline (624.015 us; speedup 1.0000x reference)
//
#include <hip/hip_runtime.h>
#include <hip/hip_bf16.h>

// ---------------- problem constants ----------------
#define BB    128
#define TT    65536
#define LF    32
#define HOP   16
#define DELTA 3
#define HID   32
#define GRUH  64
#define SWIN  96          // DELTA*HOP*2
#define SHOP  48          // DELTA*HOP
#define NF    4095        // (TT-LF)/HOP + 1
#define NS    1364        // (TT-SWIN)/SHOP + 1

// ---- chunked-scan parameters (r10-measured best: C=128/O=64) ----
#define K2C    128
#define K2O    64
#define NCHUNK ((NS + K2C - 1) / K2C)   // 11

// ---------------- ws layout (float indices), total 178.8 MB (proven safe) ----
#define GI_BASE   0ull
#define HS_BASE   (GI_BASE + (unsigned long long)BB*NS*192)

typedef float v2f __attribute__((ext_vector_type(2)));

__device__ __forceinline__ float sigmoidf_(float x) {
    return __builtin_amdgcn_rcpf(1.f + __builtin_amdgcn_exp2f(-1.44269504f * x));
}
__device__ __forceinline__ float tanhf_(float x) {
    return 1.f - 2.f * __builtin_amdgcn_rcpf(1.f + __builtin_amdgcn_exp2f(2.88539008f * x));
}
__device__ __forceinline__ v2f pkfma(v2f a, v2f b, v2f c) {
    return __builtin_elementwise_fma(a, b, c);
}

// ---------------- K1: gi[b][n][j] = b_ih[j] + slow_frame(b,n) . w_ih[j,:] ----
// Persistent grid-stride blocks + PING-PONG double-buffered segment loads:
// segment s+1 is in flight while computing from segment s (r11 falsified the
// TLP theory: 768->2304 blocks, VALUBusy stuck at 28% -> the per-segment
// vmcnt(0) stall was the limiter; ~96cyc of pkfma now covers it).
#define K1G    16
#define K1NG   ((NS + K1G - 1) / K1G)   // 86 groups
#define K1NBLK 2304

#define K1_LOAD(dst, sidx) {                                   \
    int seg_ = (sidx); if (seg_ > NS) seg_ = NS;               \
    const float4* xp_ = xb + (size_t)seg_ * 12;                \
    _Pragma("unroll")                                          \
    for (int k = 0; k < 12; ++k) dst[k] = xp_[k];              \
}
#define K1_RIGHT(src, fidx) {                                  \
    v2f a0 = pl0, a1 = pl1;                                    \
    _Pragma("unroll")                                          \
    for (int k = 0; k < 12; ++k) {                             \
        v2f p0; p0.x = src[k].x; p0.y = src[k].y;              \
        v2f p1; p1.x = src[k].z; p1.y = src[k].w;              \
        a0 = pkfma(w[24 + 2*k],     p0, a0);                   \
        a1 = pkfma(w[24 + 2*k + 1], p1, a1);                   \
    }                                                          \
    o[fidx] = a0.x + a0.y + a1.x + a1.y + bias;                \
}
#define K1_LEFT(src) {                                         \
    v2f a0 = {0.f,0.f}, a1 = {0.f,0.f};                        \
    _Pragma("unroll")                                          \
    for (int k = 0; k < 12; ++k) {                             \
        v2f p0; p0.x = src[k].x; p0.y = src[k].y;              \
        v2f p1; p1.x = src[k].z; p1.y = src[k].w;              \
        a0 = pkfma(w[2*k],     p0, a0);                        \
        a1 = pkfma(w[2*k + 1], p1, a1);                        \
    }                                                          \
    pl0 = a0; pl1 = a1;                                        \
}

__global__ __launch_bounds__(192, 1) void k1_gi(const float* __restrict__ x,
                                                const float* __restrict__ wih,
                                                const float* __restrict__ bih,
                                                float* __restrict__ gi) {
    int row = threadIdx.x;                 // 0..191 = output row

    v2f w[48];
    const v2f* wr = (const v2f*)(wih + (size_t)row * 96);
#pragma unroll
    for (int k = 0; k < 48; ++k) w[k] = wr[k];
    float bias = bih[row];

    const int nwi = K1NG * BB;             // 11008 work items
#pragma unroll 1
    for (int wi = blockIdx.x; wi < nwi; wi += K1NBLK) {
        int b  = wi & (BB - 1);
        int n0 = (wi >> 7) * K1G;
        const float4* xb = (const float4*)(x + (size_t)b * TT);

        float o[K1G];
        v2f pl0 = {0.f,0.f}, pl1 = {0.f,0.f};
        float4 A[12], Bf[12];
        K1_LOAD(A, n0)                      // segment 0
#pragma unroll 1
        for (int s = 0; s < K1G; s += 2) {
            K1_LOAD(Bf, n0 + s + 1)         // prefetch seg s+1
            if (s > 0) K1_RIGHT(A, s - 1)   // finish frame s-1 from seg s
            K1_LEFT(A)                      // open frame s from seg s
            K1_LOAD(A, n0 + s + 2)          // prefetch seg s+2
            K1_RIGHT(Bf, s)                 // finish frame s from seg s+1
            K1_LEFT(Bf)                     // open frame s+1 from seg s+1
        }
        K1_RIGHT(A, K1G - 1)                // finish frame 15 from seg 16

        float* gout = gi + ((size_t)b * NS + n0) * 192 + row;
#pragma unroll
        for (int s = 0; s < K1G; ++s)
            if (n0 + s < NS) gout[(size_t)s * 192] = o[s];
    }
}

// ---------------- K2: chunked GRU scan (r7 structure, r10 params) -----------
__global__ __launch_bounds__(64) void k2_scan(const float* __restrict__ whh,
                                              const float* __restrict__ bhh,
                                              const float* __restrict__ gi,
                                              float* __restrict__ hs) {
    int c = blockIdx.x;
    int b = blockIdx.y;
    int j = threadIdx.x;
    __shared__ __align__(16) float hsh[GRUH];

    int eStart = c * K2C;
    int eEnd   = eStart + K2C; if (eEnd > NS) eEnd = NS;
    int t0     = eStart - K2O; if (t0 < 0) t0 = 0;

    v2f wr[32], wz[32], wn[32];
    const v2f* rr = (const v2f*)(whh + (size_t)j * 64);
    const v2f* rz = (const v2f*)(whh + (size_t)(64 + j) * 64);
    const v2f* rn = (const v2f*)(whh + (size_t)(128 + j) * 64);
#pragma unroll
    for (int k = 0; k < 32; ++k) { wr[k] = rr[k]; wz[k] = rz[k]; wn[k] = rn[k]; }
    float br = bhh[j], bz = bhh[64 + j], bn = bhh[128 + j];

    hsh[j] = 0.f;
    float hj = 0.f;
    const float* gp = gi + (size_t)b * NS * 192;
    float* hp = hs + (size_t)b * NS * 64 + j;

    const float* q0 = gp + (size_t)t0 * 192;
    const float* q1 = gp + (size_t)(t0 + 1) * 192;
    float g0r = q0[j], g0z = q0[64 + j], g0n = q0[128 + j];
    float g1r = q1[j], g1z = q1[64 + j], g1n = q1[128 + j];

#pragma unroll 1
    for (int t = t0; t < eEnd; ++t) {
        const float* gq = gp + (size_t)(t + 2) * 192;   // benign over-read (lands in hs)
        float g2r = gq[j], g2z = gq[64 + j], g2n = gq[128 + j];

        v2f ar0 = {0.f,0.f}, ar1 = {0.f,0.f};
        v2f az0 = {0.f,0.f}, az1 = {0.f,0.f};
        v2f an0 = {0.f,0.f}, an1 = {0.f,0.f};
        const float4* h4 = (const float4*)hsh;
#pragma unroll
        for (int k4 = 0; k4 < 16; ++k4) {
            float4 hv = h4[k4];
            v2f p0; p0.x = hv.x; p0.y = hv.y;
            v2f p1; p1.x = hv.z; p1.y = hv.w;
            ar0 = pkfma(wr[2*k4],   p0, ar0);
            ar1 = pkfma(wr[2*k4+1], p1, ar1);
            az0 = pkfma(wz[2*k4],   p0, az0);
            az1 = pkfma(wz[2*k4+1], p1, az1);
            an0 = pkfma(wn[2*k4],   p0, an0);
            an1 = pkfma(wn[2*k4+1], p1, an1);
        }
        float sr = ar0.x + ar0.y + ar1.x + ar1.y + br;
        float sz = az0.x + az0.y + az1.x + az1.y + bz;
        float sn = an0.x + an0.y + an1.x + an1.y + bn;
        float r  = sigmoidf_(g0r + sr);
        float z  = sigmoidf_(g0z + sz);
        float nn = tanhf_(fmaf(r, sn, g0n));
        hj = fmaf(z, hj - nn, nn);           // (1-z)*n + z*h
        hsh[j] = hj;                         // single wave: program-order vs reads

        if (t >= eStart) hp[(size_t)t * 64] = hj;   // emit range only

        g0r = g1r; g0z = g1z; g0n = g1n;
        g1r = g2r; g1z = g2z; g1n = g2n;
    }
}

// ---------------- K3: fused out-proj + fast path, LDS-traffic-minimized -----
// r11 diagnosis: k3 was LDS-pipe-bound (every pkfma operand from LDS).
// Changes: phase A reads x from GLOBAL (broadcast, L1-served); phases A/B
// use 2-rows-per-thread register blocking (each read feeds 2x MACs);
// phase P holds the outw row in regs, hsl read as wave-uniform broadcast.
#define SROWS 24
__global__ __launch_bounds__(256) void k3_fast(const float* __restrict__ x,
                                               const float* __restrict__ fc1w,
                                               const float* __restrict__ fc1b,
                                               const float* __restrict__ fc2w,
                                               const float* __restrict__ fc2b,
                                               const float* __restrict__ outw,
                                               const float* __restrict__ outb,
                                               const float* __restrict__ hs,
                                               float* __restrict__ out) {
    int b  = blockIdx.y;
    int m0 = blockIdx.x * 64;
    int tid = threadIdx.x;

    __shared__ __align__(16) float gbs[SROWS * 64];   // 1536 (persistent)
    __shared__ __align__(16) float scr[4160];         // union: hsl / h1s+ys

    int fbase = m0 - 1;
    int s0 = (m0 - 1) / 3 - 1; if (s0 < 0) s0 = 0;

    // ---- phase P: eps rows [s0, s0+SROWS) ----
    {
        float* hsl = scr;                  // [SROWS][64]
        const float* hsb = hs + (size_t)b * NS * 64;
        for (int i = tid; i < SROWS * 64; i += 256) {
            int si = i >> 6, k = i & 63;
            int t = s0 + si;
            hsl[i] = (t < NS) ? hsb[(size_t)t * 64 + k] : 0.f;
        }
        int o = tid & 63, q = tid >> 6;
        v2f wo[32];                        // outw row o in regs (dies before phase F)
        const v2f* owr = (const v2f*)(outw + (size_t)o * 64);
#pragma unroll
        for (int k = 0; k < 32; ++k) wo[k] = owr[k];
        float bias = outb[o];
        __syncthreads();
        for (int si = q; si < SROWS; si += 4) {
            const float4* h4 = (const float4*)(hsl + si * 64);  // wave-uniform bcast
            v2f a0 = {0.f,0.f}, a1 = {0.f,0.f};
#pragma unroll
            for (int k = 0; k < 16; ++k) {
                float4 hv = h4[k];
                v2f p0; p0.x = hv.x; p0.y = hv.y;
                v2f p1; p1.x = hv.z; p1.y = hv.w;
                a0 = pkfma(wo[2*k],   p0, a0);
                a1 = pkfma(wo[2*k+1], p1, a1);
            }
            gbs[si * 64 + o] = a0.x + a0.y + a1.x + a1.y + bias;
        }
        __syncthreads();   // gbs ready; scr free
    }

    // ---- phase F setup: 2 fc rows per thread ----
    float* h1s = scr;                  // 65*32 = 2080
    float* ys  = scr + 2080;           // 65*32 = 2080

    int j2 = tid & 15;                 // owns rows j2 and j2+16
    int fi = tid >> 4;                 // 16 frame-slots
    v2f w1a[16], w1b[16], w2a[16], w2b[16];
    {
        const v2f* r1a = (const v2f*)(fc1w + (size_t)j2 * 32);
        const v2f* r1b = (const v2f*)(fc1w + (size_t)(j2 + 16) * 32);
        const v2f* r2a = (const v2f*)(fc2w + (size_t)j2 * 32);
        const v2f* r2b = (const v2f*)(fc2w + (size_t)(j2 + 16) * 32);
#pragma unroll
        for (int k = 0; k < 16; ++k) {
            w1a[k] = r1a[k]; w1b[k] = r1b[k];
            w2a[k] = r2a[k]; w2b[k] = r2b[k];
        }
    }
    float b1a = fc1b[j2], b1b = fc1b[j2 + 16];
    float b2a = fc2b[j2], b2b = fc2b[j2 + 16];
    const float* xb = x + (size_t)b * TT;

    // phase A: h1 = relu(g*fc1 + b)   (x from global: broadcast, L1-served)
    for (int ff = fi; ff < 65; ff += 16) {
        int f = fbase + ff;
        float va = 0.f, vb = 0.f;
        if (f >= 0 && f < NF) {
            const float4* xp = (const float4*)(xb + (size_t)f * HOP);  // 64B-aligned
            float4 xv[8];
#pragma unroll
            for (int k = 0; k < 8; ++k) xv[k] = xp[k];
            v2f a0 = {0.f,0.f}, a1 = {0.f,0.f};
            v2f c0 = {0.f,0.f}, c1 = {0.f,0.f};
#pragma unroll
            for (int k = 0; k < 8; ++k) {
                v2f p0; p0.x = xv[k].x; p0.y = xv[k].y;
                v2f p1; p1.x = xv[k].z; p1.y = xv[k].w;
                a0 = pkfma(w1a[2*k],   p0, a0);
                a1 = pkfma(w1a[2*k+1], p1, a1);
                c0 = pkfma(w1b[2*k],   p0, c0);
                c1 = pkfma(w1b[2*k+1], p1, c1);
            }
            float acca = a0.x + a0.y + a1.x + a1.y + b1a;
            float accb = c0.x + c0.y + c1.x + c1.y + b1b;
            int sidx = f / DELTA - 1; if (sidx < 0) sidx = 0;
            const float* gp = gbs + (sidx - s0) * 64;
            va = fmaxf(fmaf(gp[j2],      acca, gp[32 + j2]),      0.f);
            vb = fmaxf(fmaf(gp[16 + j2], accb, gp[48 + j2]),      0.f);
        }
        h1s[ff * 32 + j2]      = va;
        h1s[ff * 32 + 16 + j2] = vb;
    }
    __syncthreads();

    // phase B: y = h1 @ fc2^T + fc2_b
    for (int ff = fi; ff < 65; ff += 16) {
        int f = fbase + ff;
        float va = 0.f, vb = 0.f;
        if (f >= 0 && f < NF) {
            const float4* hf4 = (const float4*)(h1s + ff * 32);
            v2f a0 = {0.f,0.f}, a1 = {0.f,0.f};
            v2f c0 = {0.f,0.f}, c1 = {0.f,0.f};
#pragma unroll
            for (int k = 0; k < 8; ++k) {
                float4 hv = hf4[k];
                v2f p0; p0.x = hv.x; p0.y = hv.y;
                v2f p1; p1.x = hv.z; p1.y = hv.w;
                a0 = pkfma(w2a[2*k],   p0, a0);
                a1 = pkfma(w2a[2*k+1], p1, a1);
                c0 = pkfma(w2b[2*k],   p0, c0);
                c1 = pkfma(w2b[2*k+1], p1, c1);
            }
            va = a0.x + a0.y + a1.x + a1.y + b2a;
            vb = c0.x + c0.y + c1.x + c1.y + b2b;
        }
        ys[ff * 32 + j2]      = va;
        ys[ff * 32 + 16 + j2] = vb;
    }
    __syncthreads();

    // phase C: overlap-add -> out (fp32)
    float* ob = out + (size_t)b * TT + (size_t)m0 * HOP;
    for (int i = tid; i < 64 * 16; i += 256) {
        int ml = i >> 4, ii = i & 15;
        ob[i] = ys[(ml + 1) * 32 + ii] + ys[ml * 32 + 16 + ii];
    }
}

// ---------------- launcher ----------------
extern "C" void kernel_launch(void* const* d_in, const int* in_sizes, int n_in,
                              void* d_out, int out_size, void* d_ws, size_t ws_size,
                              hipStream_t stream) {
    const float* x     = (const float*)d_in[0];
    const float* fc1w  = (const float*)d_in[1];
    const float* fc1b  = (const float*)d_in[2];
    const float* fc2w  = (const float*)d_in[3];
    const float* fc2b  = (const float*)d_in[4];
    const float* wih   = (const float*)d_in[5];
    const float* whh   = (const float*)d_in[6];
    const float* bih   = (const float*)d_in[7];
    const float* bhh   = (const float*)d_in[8];
    const float* outw  = (const float*)d_in[9];
    const float* outb  = (const float*)d_in[10];

    float* ws  = (float*)d_ws;
    float* gi  = ws + GI_BASE;
    float* hs  = ws + HS_BASE;
    float* out = (float*)d_out;

    k1_gi<<<K1NBLK, 192, 0, stream>>>(x, wih, bih, gi);

    k2_scan<<<dim3(NCHUNK, BB), 64, 0, stream>>>(whh, bhh, gi, hs);

    k3_fast<<<dim3((NF + 1) / 64, BB), 256, 0, stream>>>(x, fc1w, fc1b, fc2w, fc2b,
                                                         outw, outb, hs, out);
}